// Round 13
// baseline (1995.295 us; speedup 1.0000x reference)
//
#include <hip/hip_runtime.h>
#include <math.h>

#define S_LEN 128
#define D_MODEL 512
#define B_SZ 256
#define NHEADS 8
#define HD 64
#define DFFN 2048
#define PI_D 3.14159265358979323846
#define DK_ITERS 128
#define JACOBI_SWEEPS 9

typedef _Float16 f16x8 __attribute__((ext_vector_type(8)));
typedef _Float16 f16x4 __attribute__((ext_vector_type(4)));
typedef float f32x4 __attribute__((ext_vector_type(4)));

// ---- async global->LDS (16B per lane), dest = uniform base + lane*16 ------
__device__ __forceinline__ void gl_lds(const _Float16* g, _Float16* l) {
    __builtin_amdgcn_global_load_lds(
        (const __attribute__((address_space(1))) void*)g,
        (__attribute__((address_space(3))) void*)l, 16, 0, 0);
}

// ---------------- split: fp32 -> (hi, lo) fp16 ------------------------------
__global__ __launch_bounds__(256) void cvt_split(const float* __restrict__ in,
        _Float16* __restrict__ hi, _Float16* __restrict__ lo, int n4)
{
    const int i = blockIdx.x * 256 + threadIdx.x;
    if (i >= n4) return;
    float4 v = ((const float4*)in)[i];
    f16x4 h, l;
    _Float16 h0 = (_Float16)v.x; h[0] = h0; l[0] = (_Float16)(v.x - (float)h0);
    _Float16 h1 = (_Float16)v.y; h[1] = h1; l[1] = (_Float16)(v.y - (float)h1);
    _Float16 h2 = (_Float16)v.z; h[2] = h2; l[2] = (_Float16)(v.z - (float)h2);
    _Float16 h3 = (_Float16)v.w; h[3] = h3; l[3] = (_Float16)(v.w - (float)h3);
    ((f16x4*)hi)[i] = h;
    ((f16x4*)lo)[i] = l;
}

// ---------------- MFMA GEMM: C[M,N] = A @ W^T + bias ------------------------
// A,W pre-split fp16 hi/lo. 3 MFMA passes (hh+hl+lh), fp32 accum.
// 128x128 tile, BK=32, 256 thr = 4 waves (2x2 of 64x64).
// DUAL-PIPE OPERANDS (r13): A staged in LDS (32KB dbuf, r9-proven swizzle +
// gl_lds); W streamed global->register double-buffered (r10-proven LOADSET,
// B-side only). Splits the split-GEMM's operand traffic across the LDS and
// L2 pipes, which run concurrently — r9 was 2x LDS-bound, r10 2x L2-bound.
// Sync structure unchanged: stage+loads BEFORE compute, one __syncthreads
// AFTER compute per tile. Arithmetic bit-identical to r9/r12.
// OUTMODE: 0 = fp32 out; 2 = split fp16 h/l out with ReLU.

#define LOADB(BH, BL, KT) do {                                                \
    const size_t kk_ = (size_t)(KT) * 32;                                     \
    _Pragma("unroll")                                                         \
    for (int n_ = 0; n_ < 4; ++n_) {                                          \
        BH[n_] = *(const f16x8*)(Whg + boff + (size_t)n_ * 16 * K + kk_);     \
        BL[n_] = *(const f16x8*)(Wlg + boff + (size_t)n_ * 16 * K + kk_);     \
    }                                                                         \
} while (0)

#define COMPUTE_T(BUF, BH, BL) do {                                           \
    f16x8 afh[4], afl[4];                                                     \
    _Pragma("unroll")                                                         \
    for (int m_ = 0; m_ < 4; ++m_) {                                          \
        const int e = (wr * 64 + m_ * 16 + fr) * 32 + koff;                   \
        afh[m_] = *(const f16x8*)&lds[BUF][0][e];                             \
        afl[m_] = *(const f16x8*)&lds[BUF][1][e];                             \
    }                                                                         \
    _Pragma("unroll")                                                         \
    for (int m_ = 0; m_ < 4; ++m_)                                            \
    _Pragma("unroll")                                                         \
    for (int n_ = 0; n_ < 4; ++n_) {                                          \
        acc[m_][n_] = __builtin_amdgcn_mfma_f32_16x16x32_f16(afh[m_], BH[n_], acc[m_][n_], 0, 0, 0); \
        acc[m_][n_] = __builtin_amdgcn_mfma_f32_16x16x32_f16(afh[m_], BL[n_], acc[m_][n_], 0, 0, 0); \
        acc[m_][n_] = __builtin_amdgcn_mfma_f32_16x16x32_f16(afl[m_], BH[n_], acc[m_][n_], 0, 0, 0); \
    }                                                                         \
} while (0)

template<int OUTMODE>
__global__ __launch_bounds__(256) void gemm_mfma(
        const _Float16* __restrict__ Ahg, const _Float16* __restrict__ Alg,
        const _Float16* __restrict__ Whg, const _Float16* __restrict__ Wlg,
        const float* __restrict__ bias, float* __restrict__ Cf,
        _Float16* __restrict__ Ch, _Float16* __restrict__ Cl,
        int M, int N, int K)
{
    __shared__ _Float16 lds[2][2][4096];   // [buf][Ah,Al][128 rows x 32]
    const int t = threadIdx.x;
    const int lane = t & 63;
    const int w = t >> 6;
    const int wr = w >> 1, wc = w & 1;
    const int fr = lane & 15;

    // XCD-aware bijective swizzle of the linearized block id (T1 / m204)
    int bid = blockIdx.y * gridDim.x + blockIdx.x;
    {
        const int nwg = gridDim.x * gridDim.y;
        const int q = nwg >> 3, r = nwg & 7;
        const int xcd = bid & 7, off = bid >> 3;
        bid = (xcd < r) ? (xcd * (q + 1) + off)
                        : (r * (q + 1) + (xcd - r) * q + off);
    }
    const int row0 = (bid / gridDim.x) * 128, col0 = (bid % gridDim.x) * 128;

    // ---- A staging: wave w stages array (w>>1) rows (w&1)*64 .. +63 -------
    const _Float16* gsrcA = (w < 2) ? Ahg : Alg;
    const int arr = (w >> 1);                    // 0 = Ah, 1 = Al
    const int rsub = (w & 1) * 64;               // row sub-block base
    const int lr16 = lane >> 2;                  // row within 16-row pass
    const int sel_s = (lr16 >> 1) & 3;           // swizzle sel (pass-invariant)
    const int lcs = ((lane & 3) ^ sel_s) * 8;    // pre-swizzled global chunk

    auto stage = [&](int buf, int kt) {
        const _Float16* srcb = gsrcA + (size_t)(row0 + rsub + lr16) * K
                               + (kt << 5) + lcs;
        _Float16* dstb = &lds[buf][arr][rsub * 32 + lane * 8];
#pragma unroll
        for (int p = 0; p < 4; ++p)
            gl_lds(srcb + (size_t)p * 16 * K, dstb + p * 512);
    };

    // ---- W register-stream offsets ----------------------------------------
    const int kg = (lane >> 4) * 8;
    const size_t boff = (size_t)(col0 + wc * 64 + fr) * K + kg;

    f32x4 acc[4][4];
#pragma unroll
    for (int m = 0; m < 4; ++m)
#pragma unroll
        for (int n = 0; n < 4; ++n) acc[m][n] = (f32x4)0.f;

    float bv[4];
#pragma unroll
    for (int n = 0; n < 4; ++n) bv[n] = bias[col0 + wc * 64 + n * 16 + fr];

    // read-side swizzled k-offset: chunk = (lane>>4) ^ ((row>>1)&3)
    const int sel_r = (fr >> 1) & 3;
    const int koff = ((lane >> 4) ^ sel_r) << 3;

    f16x8 bh0[4], bl0[4], bh1[4], bl1[4];

    const int NT = K >> 5;                 // 16 or 64 (even)
    stage(0, 0);
    LOADB(bh0, bl0, 0);
    __syncthreads();                       // drain prologue A + fence

    for (int kt = 0; kt < NT; kt += 2) {
        if (kt + 1 < NT) { stage(1, kt + 1); LOADB(bh1, bl1, kt + 1); }
        COMPUTE_T(0, bh0, bl0);
        __syncthreads();
        if (kt + 1 < NT) {
            if (kt + 2 < NT) { stage(0, kt + 2); LOADB(bh0, bl0, kt + 2); }
            COMPUTE_T(1, bh1, bl1);
            __syncthreads();
        }
    }

#pragma unroll
    for (int m = 0; m < 4; ++m) {
        const int rowc = row0 + wr * 64 + m * 16 + ((lane >> 4) << 2);
#pragma unroll
        for (int n = 0; n < 4; ++n) {
            const int colc = col0 + wc * 64 + n * 16 + fr;
#pragma unroll
            for (int j = 0; j < 4; ++j) {
                float v = acc[m][n][j] + bv[n];
                if (OUTMODE == 2) {
                    v = fmaxf(v, 0.f);
                    const size_t idx = (size_t)(rowc + j) * N + colc;
                    _Float16 h = (_Float16)v;
                    Ch[idx] = h;
                    Cl[idx] = (_Float16)(v - (float)h);
                } else {
                    Cf[(size_t)(rowc + j) * N + colc] = v;
                }
            }
        }
    }
}

// ---------------- fp32 GEMM (tiny head projections) -------------------------
template<int RELU>
__global__ __launch_bounds__(256) void gemm_bias(const float* __restrict__ A,
        const float* __restrict__ W, const float* __restrict__ bias,
        float* __restrict__ C, int M, int N, int K)
{
    __shared__ float As[8][128];
    __shared__ float Ws[8][128];
    const int tid = threadIdx.x;
    const int tn = tid & 15, tm = tid >> 4;
    const int row0 = blockIdx.y * 128, col0 = blockIdx.x * 128;
    const int lrr = tid >> 1, lcc = (tid & 1) * 4;
    const float* Ap = A + (size_t)(row0 + lrr) * K + lcc;
    const float* Wp = W + (size_t)(col0 + lrr) * K + lcc;
    float acc[8][8];
#pragma unroll
    for (int i = 0; i < 8; ++i)
#pragma unroll
        for (int j = 0; j < 8; ++j) acc[i][j] = 0.f;

    for (int k0 = 0; k0 < K; k0 += 8) {
        float4 av = *(const float4*)(Ap + k0);
        float4 wv = *(const float4*)(Wp + k0);
        __syncthreads();
        As[lcc + 0][lrr] = av.x; As[lcc + 1][lrr] = av.y;
        As[lcc + 2][lrr] = av.z; As[lcc + 3][lrr] = av.w;
        Ws[lcc + 0][lrr] = wv.x; Ws[lcc + 1][lrr] = wv.y;
        Ws[lcc + 2][lrr] = wv.z; Ws[lcc + 3][lrr] = wv.w;
        __syncthreads();
#pragma unroll
        for (int k = 0; k < 8; ++k) {
            float ar[8], wrg[8];
#pragma unroll
            for (int i = 0; i < 8; ++i) ar[i] = As[k][tm * 8 + i];
#pragma unroll
            for (int j = 0; j < 8; ++j) wrg[j] = Ws[k][tn * 8 + j];
#pragma unroll
            for (int i = 0; i < 8; ++i)
#pragma unroll
                for (int j = 0; j < 8; ++j)
                    acc[i][j] = fmaf(ar[i], wrg[j], acc[i][j]);
        }
    }
#pragma unroll
    for (int i = 0; i < 8; ++i) {
        const int r = row0 + tm * 8 + i;
#pragma unroll
        for (int j = 0; j < 8; ++j) {
            const int c = col0 + tn * 8 + j;
            float v = acc[i][j] + bias[c];
            if (RELU) v = fmaxf(v, 0.f);
            C[(size_t)r * N + c] = v;
        }
    }
}

// ---------------- Attention (writes split fp16 h/l output) ------------------
__global__ __launch_bounds__(128) void attn_kernel(const float* __restrict__ qkv,
        _Float16* __restrict__ oh, _Float16* __restrict__ ol)
{
    const int bh = blockIdx.x;
    const int b = bh >> 3, hh = bh & 7;
    const int t = threadIdx.x;
    __shared__ float Ks[S_LEN][HD];
    __shared__ float Vs[S_LEN][HD];
    const float* base = qkv + (size_t)b * S_LEN * (3 * D_MODEL);
    const float* krow = base + (size_t)t * (3 * D_MODEL) + D_MODEL + hh * HD;
    const float* vrow = base + (size_t)t * (3 * D_MODEL) + 2 * D_MODEL + hh * HD;
#pragma unroll
    for (int d = 0; d < HD; d += 4) {
        *(float4*)&Ks[t][d] = *(const float4*)(krow + d);
        *(float4*)&Vs[t][d] = *(const float4*)(vrow + d);
    }
    float q[HD];
    const float* qrow = base + (size_t)t * (3 * D_MODEL) + hh * HD;
#pragma unroll
    for (int d = 0; d < HD; d += 4) {
        float4 v4 = *(const float4*)(qrow + d);
        q[d] = v4.x; q[d + 1] = v4.y; q[d + 2] = v4.z; q[d + 3] = v4.w;
    }
    __syncthreads();
    float m = -1e30f, l = 0.f;
    float oacc[HD];
#pragma unroll
    for (int d = 0; d < HD; ++d) oacc[d] = 0.f;
    for (int j = 0; j < S_LEN; ++j) {
        float s = 0.f;
#pragma unroll
        for (int d = 0; d < HD; ++d) s = fmaf(q[d], Ks[j][d], s);
        s *= 0.125f;
        const float nm = fmaxf(m, s);
        const float sc = expf(m - nm);
        const float p = expf(s - nm);
        l = l * sc + p;
#pragma unroll
        for (int d = 0; d < HD; ++d) oacc[d] = oacc[d] * sc + p * Vs[j][d];
        m = nm;
    }
    const float inv = 1.f / l;
    const size_t ob = (size_t)b * S_LEN * D_MODEL + (size_t)t * D_MODEL + hh * HD;
#pragma unroll
    for (int d = 0; d < HD; ++d) {
        const float v = oacc[d] * inv;
        const _Float16 h = (_Float16)v;
        oh[ob + d] = h;
        ol[ob + d] = (_Float16)(v - (float)h);
    }
}

// ---------------- residual add + LayerNorm (+ optional split out) ----------
template<int SPLIT>
__global__ __launch_bounds__(128) void add_ln_kernel(const float* __restrict__ a,
        const float* __restrict__ bb, const float* __restrict__ g,
        const float* __restrict__ be, float* __restrict__ out,
        _Float16* __restrict__ oh, _Float16* __restrict__ ol)
{
    __shared__ float red[2];
    const int row = blockIdx.x, t = threadIdx.x;
    float4 av = *(const float4*)(a + (size_t)row * D_MODEL + t * 4);
    float4 bv = *(const float4*)(bb + (size_t)row * D_MODEL + t * 4);
    float x0 = av.x + bv.x, x1 = av.y + bv.y, x2 = av.z + bv.z, x3 = av.w + bv.w;
    float ssum = x0 + x1 + x2 + x3;
#pragma unroll
    for (int off = 32; off >= 1; off >>= 1) ssum += __shfl_xor(ssum, off);
    if ((t & 63) == 0) red[t >> 6] = ssum;
    __syncthreads();
    const float mean = (red[0] + red[1]) * (1.f / 512.f);
    __syncthreads();
    float d0 = x0 - mean, d1 = x1 - mean, d2 = x2 - mean, d3 = x3 - mean;
    float sq = d0 * d0 + d1 * d1 + d2 * d2 + d3 * d3;
#pragma unroll
    for (int off = 32; off >= 1; off >>= 1) sq += __shfl_xor(sq, off);
    if ((t & 63) == 0) red[t >> 6] = sq;
    __syncthreads();
    const float var = (red[0] + red[1]) * (1.f / 512.f);
    const float inv = 1.0f / sqrtf(var + 1e-5f);
    float4 gv = *(const float4*)(g + t * 4);
    float4 bev = *(const float4*)(be + t * 4);
    float4 ov = make_float4(d0 * inv * gv.x + bev.x, d1 * inv * gv.y + bev.y,
                            d2 * inv * gv.z + bev.z, d3 * inv * gv.w + bev.w);
    *(float4*)(out + (size_t)row * D_MODEL + t * 4) = ov;
    if (SPLIT) {
        f16x4 h, l;
        _Float16 h0 = (_Float16)ov.x; h[0] = h0; l[0] = (_Float16)(ov.x - (float)h0);
        _Float16 h1 = (_Float16)ov.y; h[1] = h1; l[1] = (_Float16)(ov.y - (float)h1);
        _Float16 h2 = (_Float16)ov.z; h[2] = h2; l[2] = (_Float16)(ov.z - (float)h2);
        _Float16 h3 = (_Float16)ov.w; h[3] = h3; l[3] = (_Float16)(ov.w - (float)h3);
        *(f16x4*)&oh[(size_t)row * D_MODEL + t * 4] = h;
        *(f16x4*)&ol[(size_t)row * D_MODEL + t * 4] = l;
    }
}

// ---------------- mean over sequence ---------------------------------------
__global__ __launch_bounds__(128) void pool_kernel(const float* __restrict__ x,
                                                   float* __restrict__ pooled)
{
    const int b = blockIdx.x, t = threadIdx.x;
    float4 acc = make_float4(0.f, 0.f, 0.f, 0.f);
    const float* base = x + (size_t)b * S_LEN * D_MODEL + t * 4;
    for (int s = 0; s < S_LEN; ++s) {
        float4 v = *(const float4*)(base + (size_t)s * D_MODEL);
        acc.x += v.x; acc.y += v.y; acc.z += v.z; acc.w += v.w;
    }
    const float sc = 1.f / 128.f;
    float4 ov = make_float4(acc.x * sc, acc.y * sc, acc.z * sc, acc.w * sc);
    *(float4*)(pooled + (size_t)b * D_MODEL + t * 4) = ov;
}

// ---------------- root-MUSIC: parallel Jacobi + register-shuffle DK --------
__global__ __launch_bounds__(64) void music_kernel(const float* __restrict__ RxRy,
                                                   float* __restrict__ hbuf)
{
    const int pb = blockIdx.x;          // 0..511
    const int b = pb >> 1, which = pb & 1;
    const float* src = RxRy + (size_t)which * (B_SZ * 128) + (size_t)b * 128;
    const int t = threadIdx.x;
    const int i = t >> 3, j = t & 7;

    __shared__ double KRe[8][8], KIm[8][8];
    __shared__ double Ar[8][8], Ai[8][8], Vr[8][8], Vi[8][8];
    __shared__ double Fre[8][8], Fim[8][8];
    __shared__ double rc[4], rs[4], rer[4], rei[4];
    __shared__ double cr[15], ci[15], br[14], bi[14], zr[14], zi[14];
    __shared__ int topidx[3];

    KRe[i][j] = (double)src[i * 8 + j];
    KIm[i][j] = (double)src[64 + i * 8 + j];
    __syncthreads();
    {   // Rz = K^H K + I ; V = I
        double sre = (i == j) ? 1.0 : 0.0, sim = 0.0;
        for (int r = 0; r < 8; ++r) {
            const double ar = KRe[r][i], ai = KIm[r][i];
            const double xr = KRe[r][j], xi = KIm[r][j];
            sre += ar * xr + ai * xi;
            sim += ar * xi - ai * xr;
        }
        Ar[i][j] = sre; Ai[i][j] = sim;
        Vr[i][j] = (i == j) ? 1.0 : 0.0;
        Vi[i][j] = 0.0;
    }
    __syncthreads();

    // parallel-order Jacobi: JACOBI_SWEEPS x 7 rounds x 4 disjoint rotations
    for (int sw = 0; sw < JACOBI_SWEEPS; ++sw)
    for (int rr = 0; rr < 7; ++rr) {
        int pp[4], qq[4];
        pp[0] = 0;                 qq[0] = (rr + 6) % 7 + 1;
        pp[1] = rr % 7 + 1;        qq[1] = (rr + 5) % 7 + 1;
        pp[2] = (rr + 1) % 7 + 1;  qq[2] = (rr + 4) % 7 + 1;
        pp[3] = (rr + 2) % 7 + 1;  qq[3] = (rr + 3) % 7 + 1;
        if (t < 4) {
            const int p = pp[t], q = qq[t];
            const double gre = Ar[p][q], gim = Ai[p][q];
            const double r = sqrt(gre * gre + gim * gim);
            double c, s, er, ei;
            if (r < 1e-60) { c = 1.0; s = 0.0; er = 1.0; ei = 0.0; }
            else {
                const double tau = (Ar[p][p] - Ar[q][q]) / (2.0 * r);
                const double tt = ((tau >= 0.0) ? 1.0 : -1.0) /
                                  (fabs(tau) + sqrt(1.0 + tau * tau));
                c = 1.0 / sqrt(1.0 + tt * tt); s = tt * c;
                er = gre / r; ei = gim / r;
            }
            rc[t] = c; rs[t] = s; rer[t] = er; rei[t] = ei;
        }
        __syncthreads();
        int gi = 0, gj = 0;
#pragma unroll
        for (int g = 0; g < 4; ++g) {
            if (pp[g] == i || qq[g] == i) gi = g;
            if (pp[g] == j || qq[g] == j) gj = g;
        }
        const int ri_q = (qq[gi] == i), rj_q = (qq[gj] == j);
        const double ci_ = rc[gi], si_ = rs[gi], eir = rer[gi], eii = rei[gi];
        const double cj_ = rc[gj], sj_ = rs[gj], ejr = rer[gj], eji = rei[gj];
        const int Pi = pp[gi], Qi = qq[gi], Pj = pp[gj], Qj = qq[gj];

        double bPr, bPi_, bQr, bQi_;
        {
            double apr = Ar[Pi][Pj], api = Ai[Pi][Pj];
            double aqr = Ar[Pi][Qj], aqi = Ai[Pi][Qj];
            if (!rj_q) { bPr = cj_ * apr + sj_ * (ejr * aqr + eji * aqi);
                         bPi_= cj_ * api + sj_ * (ejr * aqi - eji * aqr); }
            else       { bPr = cj_ * aqr - sj_ * (ejr * apr - eji * api);
                         bPi_= cj_ * aqi - sj_ * (ejr * api + eji * apr); }
            apr = Ar[Qi][Pj]; api = Ai[Qi][Pj];
            aqr = Ar[Qi][Qj]; aqi = Ai[Qi][Qj];
            if (!rj_q) { bQr = cj_ * apr + sj_ * (ejr * aqr + eji * aqi);
                         bQi_= cj_ * api + sj_ * (ejr * aqi - eji * aqr); }
            else       { bQr = cj_ * aqr - sj_ * (ejr * apr - eji * api);
                         bQi_= cj_ * aqi - sj_ * (ejr * api + eji * apr); }
        }
        double nAr, nAi_;
        if (!ri_q) { nAr = ci_ * bPr + si_ * (eir * bQr - eii * bQi_);
                     nAi_= ci_ * bPi_+ si_ * (eir * bQi_ + eii * bQr); }
        else       { nAr = ci_ * bQr - si_ * (eir * bPr + eii * bPi_);
                     nAi_= ci_ * bQi_- si_ * (eir * bPi_ - eii * bPr); }
        double nVr, nVi_;
        {
            const double vpr = Vr[i][Pj], vpi = Vi[i][Pj];
            const double vqr = Vr[i][Qj], vqi = Vi[i][Qj];
            if (!rj_q) { nVr = cj_ * vpr + sj_ * (ejr * vqr + eji * vqi);
                         nVi_= cj_ * vpi + sj_ * (ejr * vqi - eji * vqr); }
            else       { nVr = cj_ * vqr - sj_ * (ejr * vpr - eji * vpi);
                         nVi_= cj_ * vqi - sj_ * (ejr * vpi + eji * vpr); }
        }
        __syncthreads();
        Ar[i][j] = nAr; Ai[i][j] = nAi_;
        Vr[i][j] = nVr; Vi[i][j] = nVi_;
        __syncthreads();
    }

    if (t == 0) {  // top-3 eigenvalues -> signal subspace
        bool used[8] = {false, false, false, false, false, false, false, false};
        for (int tt = 0; tt < 3; ++tt) {
            double best = -1e300; int bidx = 0;
            for (int k = 0; k < 8; ++k)
                if (!used[k] && Ar[k][k] > best) { best = Ar[k][k]; bidx = k; }
            used[bidx] = true; topidx[tt] = bidx;
        }
    }
    __syncthreads();
    {   // F = I - sum_top3 v v^H
        double fre = (i == j) ? 1.0 : 0.0, fim = 0.0;
        for (int tt = 0; tt < 3; ++tt) {
            const int e = topidx[tt];
            const double vir = Vr[i][e], vii = Vi[i][e];
            const double vjr = Vr[j][e], vji = Vi[j][e];
            fre -= vir * vjr + vii * vji;
            fim -= vii * vjr - vir * vji;
        }
        Fre[i][j] = fre; Fim[i][j] = fim;
    }
    __syncthreads();
    if (t < 15) {  // coeffs: diagonal sums
        const int o = t - 7;
        double sre = 0.0, sim = 0.0;
        for (int r = 0; r < 8; ++r) {
            const int cc = r + o;
            if (cc >= 0 && cc < 8) { sre += Fre[r][cc]; sim += Fim[r][cc]; }
        }
        cr[t] = sre; ci[t] = sim;
    }
    __syncthreads();
    if (t < 14) {  // monic normalize
        const double den = cr[0] * cr[0] + ci[0] * ci[0];
        const double nr = cr[t + 1], ni = ci[t + 1];
        br[t] = (nr * cr[0] + ni * ci[0]) / den;
        bi[t] = (ni * cr[0] - nr * ci[0]) / den;
    }
    __syncthreads();

    // ---- decimated Durand-Kerner, roots in registers, convergence-gated ---
    const int rt = t >> 2, jj = t & 3;
    const int rsafe = (rt < 14) ? rt : 0;
    double A_r[4], A_i[4];
#pragma unroll
    for (int m = 0; m < 4; ++m) {
        const int idx = 13 - 4 * m - jj;
        if (idx >= 0)       { A_r[m] = br[idx]; A_i[m] = bi[idx]; }
        else if (idx == -1) { A_r[m] = 1.0;     A_i[m] = 0.0; }
        else                { A_r[m] = 0.0;     A_i[m] = 0.0; }
    }

    double zre, zim;
    {   // init root rsafe: (0.4+0.9i)^(rsafe+1)
        double zr_ = 1.0, zi_ = 0.0;
        for (int k = 0; k <= rsafe; ++k) {
            const double a2 = zr_ * 0.4 - zi_ * 0.9;
            zi_ = zr_ * 0.9 + zi_ * 0.4;
            zr_ = a2;
        }
        zre = zr_; zim = zi_;
    }

    for (int it = 0; it < DK_ITERS; ++it) {
        const double z2r = zre * zre - zim * zim, z2i = 2.0 * zre * zim;
        const double yr = z2r * z2r - z2i * z2i, yi = 2.0 * z2r * z2i;
        double wre = A_r[3], wim = A_i[3];
#pragma unroll
        for (int m = 2; m >= 0; --m) {
            const double tr = wre * yr - wim * yi + A_r[m];
            wim = wre * yi + wim * yr + A_i[m];
            wre = tr;
        }
        double pr, pi;
        if (jj == 0)      { pr = wre; pi = wim; }
        else if (jj == 1) { pr = wre * zre - wim * zim; pi = wre * zim + wim * zre; }
        else if (jj == 2) { pr = wre * z2r - wim * z2i; pi = wre * z2i + wim * z2r; }
        else { const double z3r = z2r * zre - z2i * zim, z3i = z2r * zim + z2i * zre;
               pr = wre * z3r - wim * z3i; pi = wre * z3i + wim * z3r; }
        pr += __shfl_xor(pr, 1); pi += __shfl_xor(pi, 1);
        pr += __shfl_xor(pr, 2); pi += __shfl_xor(pi, 2);
        double dr = 1.0, di = 0.0;
#pragma unroll
        for (int q = 0; q < 4; ++q) {
            const int k = jj * 4 + q;                 // 0..15
            const double zkr = __shfl(zre, 4 * k);    // root k lives in lane 4k
            const double zki = __shfl(zim, 4 * k);
            const bool val = (k < 14) && (k != rsafe);
            const double exr = val ? (zre - zkr) : 1.0;
            const double exi = val ? (zim - zki) : 0.0;
            const double trd = dr * exr - di * exi;
            di = dr * exi + di * exr;
            dr = trd;
        }
        {
            double orr = __shfl_xor(dr, 1), oii = __shfl_xor(di, 1);
            double tr = dr * orr - di * oii; di = dr * oii + di * orr; dr = tr;
            orr = __shfl_xor(dr, 2); oii = __shfl_xor(di, 2);
            tr = dr * orr - di * oii; di = dr * oii + di * orr; dr = tr;
        }
        const double dd = dr * dr + di * di;
        double dzr, dzi;
        if (dd > 1e-260) {
            dzr = (pr * dr + pi * di) / dd;
            dzi = (pi * dr - pr * di) / dd;
        } else {
            dzr = -1e-8; dzi = 1e-8;
        }
        zre -= dzr; zim -= dzi;
        const bool conv = (rt >= 14) || (dzr * dzr + dzi * dzi < 1e-24);
        if (__all(conv)) break;
    }
    if (rt < 14 && jj == 0) { zr[rt] = zre; zi[rt] = zim; }
    __syncthreads();

    if (t == 0) {
        double keyv[14]; bool used[14];
        for (int k = 0; k < 14; ++k) {
            const double mag = sqrt(zr[k] * zr[k] + zi[k] * zi[k]);
            keyv[k] = fabs(mag - 1.0) + ((mag < 1.0) ? 0.0 : 1e6);
            used[k] = false;
        }
        for (int tt = 0; tt < 3; ++tt) {
            double best = 1e300; int bidx = 0;
            for (int k = 0; k < 14; ++k)
                if (!used[k] && keyv[k] < best) { best = keyv[k]; bidx = k; }
            used[bidx] = true;
            const double ang = atan2(zi[bidx], zr[bidx]);
            double ratio = ang / PI_D;
            if (ratio > 1.0) ratio = 1.0;
            if (ratio < -1.0) ratio = -1.0;
            hbuf[(size_t)b * 6 + which * 3 + tt] = (float)asin(ratio);
        }
    }
}

// ---------------- final MLP 6->256->256->6 ---------------------------------
__global__ __launch_bounds__(256) void mlp_kernel(const float* __restrict__ hbuf,
        const float* __restrict__ w1, const float* __restrict__ b1,
        const float* __restrict__ w2, const float* __restrict__ b2,
        const float* __restrict__ w3, const float* __restrict__ b3,
        float* __restrict__ outp)
{
    const int b = blockIdx.x, t = threadIdx.x;
    __shared__ float hin[8];
    __shared__ float h1[256];
    __shared__ float h2[256];
    if (t < 6) hin[t] = hbuf[b * 6 + t];
    __syncthreads();
    float acc = b1[t];
#pragma unroll
    for (int k = 0; k < 6; ++k) acc += hin[k] * w1[t * 6 + k];
    h1[t] = fmaxf(acc, 0.f);
    __syncthreads();
    float acc2 = b2[t];
    for (int k = 0; k < 256; ++k) acc2 += h1[k] * w2[t * 256 + k];
    h2[t] = fmaxf(acc2, 0.f);
    __syncthreads();
    if (t < 6) {
        float acc3 = b3[t];
        for (int k = 0; k < 256; ++k) acc3 += h2[k] * w3[t * 256 + k];
        if (t < 3) outp[b * 3 + t] = acc3;
        else       outp[B_SZ * 3 + b * 3 + (t - 3)] = acc3;
    }
}

// ---------------- host launcher --------------------------------------------
extern "C" void kernel_launch(void* const* d_in, const int* in_sizes, int n_in,
                              void* d_out, int out_size, void* d_ws, size_t ws_size,
                              hipStream_t stream)
{
    const float* x_in      = (const float*)d_in[0];
    const float* in_proj_w = (const float*)d_in[1];
    const float* in_proj_b = (const float*)d_in[2];
    const float* out_proj_w= (const float*)d_in[3];
    const float* out_proj_b= (const float*)d_in[4];
    const float* ln1_g     = (const float*)d_in[5];
    const float* ln1_b     = (const float*)d_in[6];
    const float* ffn_w1    = (const float*)d_in[7];
    const float* ffn_b1    = (const float*)d_in[8];
    const float* ffn_w2    = (const float*)d_in[9];
    const float* ffn_b2    = (const float*)d_in[10];
    const float* ln2_g     = (const float*)d_in[11];
    const float* ln2_b     = (const float*)d_in[12];
    const float* fcx_w     = (const float*)d_in[13];
    const float* fcx_b     = (const float*)d_in[14];
    const float* fcy_w     = (const float*)d_in[15];
    const float* fcy_b     = (const float*)d_in[16];
    const float* mlp_w1    = (const float*)d_in[17];
    const float* mlp_b1    = (const float*)d_in[18];
    const float* mlp_w2    = (const float*)d_in[19];
    const float* mlp_b2    = (const float*)d_in[20];
    const float* mlp_w3    = (const float*)d_in[21];
    const float* mlp_b3    = (const float*)d_in[22];

    // ---- workspace: split weights (static) --------------------------------
    const size_t N_IPW = 1536 * 512, N_OPW = 512 * 512;
    const size_t N_F1W = 2048 * 512, N_F2W = 512 * 2048;
    const size_t WCVT = N_IPW + N_OPW + N_F1W + N_F2W;   // 3,145,728 floats
    float* ws = (float*)d_ws;
    _Float16* ipw_h = (_Float16*)ws;
    _Float16* ipw_l = ipw_h + N_IPW;
    _Float16* opw_h = ipw_l + N_IPW;
    _Float16* opw_l = opw_h + N_OPW;
    _Float16* f1w_h = opw_l + N_OPW;
    _Float16* f1w_l = f1w_h + N_F1W;
    _Float16* f2w_h = f1w_l + N_F1W;
    _Float16* f2w_l = f2w_h + N_F2W;
    float* dyn = ws + WCVT;

    // ---- dynamic, chunked: 524288*c floats + tail -------------------------
    const size_t ws_floats = ws_size / sizeof(float);
    int c = 256;
    while (c > 1 && (size_t)524288 * (size_t)c + 262144 + WCVT > ws_floats) c >>= 1;

    float* R0     = dyn;                              // 262144c
    float* xhf    = R0 + (size_t)262144 * c;          // 32768c (xh f16)
    float* xlf    = xhf + (size_t)32768 * c;          // 32768c
    float* x1     = xlf + (size_t)32768 * c;          // 65536c fp32
    float* x1hf   = x1 + (size_t)65536 * c;           // 32768c
    float* x1lf   = x1hf + (size_t)32768 * c;         // 32768c
    float* ff2    = x1lf + (size_t)32768 * c;         // 65536c fp32
    float* pooled = ff2 + (size_t)65536 * c;          // 131072
    float* RxRy   = pooled + 131072;                  // 65536
    float* hbuf   = RxRy + 65536;                     // 1536

    float*    qkv  = R0;                              // 196608c fp32
    _Float16* oh   = (_Float16*)(R0 + (size_t)196608 * c);
    _Float16* ol   = oh + (size_t)65536 * c;
    _Float16* ff1h = (_Float16*)R0;                   // overlays qkv+o
    _Float16* ff1l = ff1h + (size_t)262144 * c;
    _Float16* xh   = (_Float16*)xhf;
    _Float16* xl   = (_Float16*)xlf;
    _Float16* x1h  = (_Float16*)x1hf;
    _Float16* x1l  = (_Float16*)x1lf;

    // ---- split weights ----------------------------------------------------
    cvt_split<<<(N_IPW / 4 + 255) / 256, 256, 0, stream>>>(in_proj_w,  ipw_h, ipw_l, N_IPW / 4);
    cvt_split<<<(N_OPW / 4 + 255) / 256, 256, 0, stream>>>(out_proj_w, opw_h, opw_l, N_OPW / 4);
    cvt_split<<<(N_F1W / 4 + 255) / 256, 256, 0, stream>>>(ffn_w1,     f1w_h, f1w_l, N_F1W / 4);
    cvt_split<<<(N_F2W / 4 + 255) / 256, 256, 0, stream>>>(ffn_w2,     f2w_h, f2w_l, N_F2W / 4);

    for (int b0 = 0; b0 < B_SZ; b0 += c) {
        const int Tc = c * S_LEN;
        const float* xc = x_in + (size_t)b0 * S_LEN * D_MODEL;
        const int n4x = Tc * D_MODEL / 4;

        // 0. split chunk input
        cvt_split<<<(n4x + 255) / 256, 256, 0, stream>>>(xc, xh, xl, n4x);
        // 1. qkv = x @ Wi^T + bi
        gemm_mfma<0><<<dim3(1536 / 128, Tc / 128), 256, 0, stream>>>(
            xh, xl, ipw_h, ipw_l, in_proj_b, qkv, nullptr, nullptr, Tc, 3 * D_MODEL, D_MODEL);
        // 2. attention -> split o
        attn_kernel<<<c * NHEADS, 128, 0, stream>>>(qkv, oh, ol);
        // 3. out proj
        gemm_mfma<0><<<dim3(512 / 128, Tc / 128), 256, 0, stream>>>(
            oh, ol, opw_h, opw_l, out_proj_b, x1, nullptr, nullptr, Tc, D_MODEL, D_MODEL);
        // 4. x1 = LN(x + proj), fp32 + split
        add_ln_kernel<1><<<Tc, 128, 0, stream>>>(xc, x1, ln1_g, ln1_b, x1, x1h, x1l);
        // 5. ff1 = relu(x1 @ W1^T + b1), split out (overlays dead qkv+o)
        gemm_mfma<2><<<dim3(DFFN / 128, Tc / 128), 256, 0, stream>>>(
            x1h, x1l, f1w_h, f1w_l, ffn_b1, nullptr, ff1h, ff1l, Tc, DFFN, D_MODEL);
        // 6. ff2 = ff1 @ W2^T + b2
        gemm_mfma<0><<<dim3(512 / 128, Tc / 128), 256, 0, stream>>>(
            ff1h, ff1l, f2w_h, f2w_l, ffn_b2, ff2, nullptr, nullptr, Tc, D_MODEL, DFFN);
        // 7. x2 = LN(x1 + ff2) in place (fp32 only)
        add_ln_kernel<0><<<Tc, 128, 0, stream>>>(x1, ff2, ln2_g, ln2_b, x1, nullptr, nullptr);
        // 8. mean pool
        pool_kernel<<<c, 128, 0, stream>>>(x1, pooled + (size_t)b0 * D_MODEL);
    }

    // 9. heads
    gemm_bias<0><<<dim3(1, 2), 256, 0, stream>>>(
        pooled, fcx_w, fcx_b, RxRy, B_SZ, 128, D_MODEL);
    gemm_bias<0><<<dim3(1, 2), 256, 0, stream>>>(
        pooled, fcy_w, fcy_b, RxRy + B_SZ * 128, B_SZ, 128, D_MODEL);
    // 10. root-MUSIC
    music_kernel<<<2 * B_SZ, 64, 0, stream>>>(RxRy, hbuf);
    // 11. final MLP
    mlp_kernel<<<B_SZ, 256, 0, stream>>>(hbuf, mlp_w1, mlp_b1, mlp_w2, mlp_b2,
                                         mlp_w3, mlp_b3, (float*)d_out);
}

// Round 14
// 1616.701 us; speedup vs baseline: 1.2342x; 1.2342x over previous
//
#include <hip/hip_runtime.h>
#include <math.h>

#define S_LEN 128
#define D_MODEL 512
#define B_SZ 256
#define NHEADS 8
#define HD 64
#define DFFN 2048
#define PI_D 3.14159265358979323846
#define DK_ITERS 128
#define JACOBI_SWEEPS 9

typedef _Float16 f16x8 __attribute__((ext_vector_type(8)));
typedef _Float16 f16x4 __attribute__((ext_vector_type(4)));
typedef float f32x4 __attribute__((ext_vector_type(4)));

// ---- async global->LDS (16B per lane), dest = uniform base + lane*16 ------
__device__ __forceinline__ void gl_lds(const _Float16* g, _Float16* l) {
    __builtin_amdgcn_global_load_lds(
        (const __attribute__((address_space(1))) void*)g,
        (__attribute__((address_space(3))) void*)l, 16, 0, 0);
}

// ---------------- split: fp32 -> (hi, lo) fp16 ------------------------------
__global__ __launch_bounds__(256) void cvt_split(const float* __restrict__ in,
        _Float16* __restrict__ hi, _Float16* __restrict__ lo, int n4)
{
    const int i = blockIdx.x * 256 + threadIdx.x;
    if (i >= n4) return;
    float4 v = ((const float4*)in)[i];
    f16x4 h, l;
    _Float16 h0 = (_Float16)v.x; h[0] = h0; l[0] = (_Float16)(v.x - (float)h0);
    _Float16 h1 = (_Float16)v.y; h[1] = h1; l[1] = (_Float16)(v.y - (float)h1);
    _Float16 h2 = (_Float16)v.z; h[2] = h2; l[2] = (_Float16)(v.z - (float)h2);
    _Float16 h3 = (_Float16)v.w; h[3] = h3; l[3] = (_Float16)(v.w - (float)h3);
    ((f16x4*)hi)[i] = h;
    ((f16x4*)lo)[i] = l;
}

// ---------------- MFMA GEMM: C[M,N] = A @ W^T + bias ------------------------
// A,W pre-split fp16 hi/lo. 3 MFMA passes (hh+hl+lh), fp32 accum.
// 128x128 tile, BK=32, 256 thr = 4 waves (2x2 of 64x64).
// global_load_lds staging, double-buffered 64KB LDS (2 blocks/CU).
// T3 2-phase + r9-proven LDS swizzle + XCD-aware bijective block swizzle.
// (r13's dual-pipe variant regressed: +64 VGPR for W reg-stream broke the
// occupancy step. This r12 configuration is the session's proven best.)
// OUTMODE: 0 = fp32 out; 2 = split fp16 h/l out with ReLU.
template<int OUTMODE>
__global__ __launch_bounds__(256) void gemm_mfma(
        const _Float16* __restrict__ Ahg, const _Float16* __restrict__ Alg,
        const _Float16* __restrict__ Whg, const _Float16* __restrict__ Wlg,
        const float* __restrict__ bias, float* __restrict__ Cf,
        _Float16* __restrict__ Ch, _Float16* __restrict__ Cl,
        int M, int N, int K)
{
    __shared__ _Float16 lds[2][4][4096];   // [buf][Ah,Al,Wh,Wl][128 rows x 32]
    const int t = threadIdx.x;
    const int lane = t & 63;
    const int w = t >> 6;
    const int wr = w >> 1, wc = w & 1;

    // XCD-aware bijective swizzle of the linearized block id (T1 / m204)
    int bid = blockIdx.y * gridDim.x + blockIdx.x;
    {
        const int nwg = gridDim.x * gridDim.y;
        const int q = nwg >> 3, r = nwg & 7;
        const int xcd = bid & 7, off = bid >> 3;
        bid = (xcd < r) ? (xcd * (q + 1) + off)
                        : (r * (q + 1) + (xcd - r) * q + off);
    }
    const int row0 = (bid / gridDim.x) * 128, col0 = (bid % gridDim.x) * 128;

    const _Float16* gptr[4] = { Ahg, Alg, Whg, Wlg };
    const int rbase = (w < 2) ? row0 : col0;
    const _Float16* gsrc = gptr[w];
    const int lr = lane >> 2;                    // row within 16-row pass
    const int sel_s = (lr >> 1) & 3;             // swizzle selector (p-invariant)
    const int lcs = (((lane & 3) ^ sel_s)) * 8;  // pre-swizzled global chunk

    auto stage = [&](int buf, int kt) {
        const _Float16* srcb = gsrc + (size_t)(rbase + lr) * K + (kt << 5) + lcs;
        _Float16* dstb = &lds[buf][w][lane * 8];
#pragma unroll
        for (int p = 0; p < 8; ++p)
            gl_lds(srcb + (size_t)p * 16 * K, dstb + p * 512);
    };

    f32x4 acc[4][4];
#pragma unroll
    for (int m = 0; m < 4; ++m)
#pragma unroll
        for (int n = 0; n < 4; ++n) acc[m][n] = (f32x4)0.f;

    const int NT = K >> 5;
    stage(0, 0);
    float bv[4];
#pragma unroll
    for (int n = 0; n < 4; ++n) bv[n] = bias[col0 + wc * 64 + n * 16 + (lane & 15)];

    __syncthreads();                     // drain prologue loads + fence

    // read-side swizzled k-offset: chunk = (lane>>4) ^ ((row>>1)&3)
    const int sel_r = ((lane & 15) >> 1) & 3;
    const int koff = (((lane >> 4) ^ sel_r)) << 3;
    for (int kt = 0; kt < NT; ++kt) {
        const int cur = kt & 1;
        if (kt + 1 < NT) stage(cur ^ 1, kt + 1);   // in flight across MFMA phase
        f16x8 afh[4], afl[4], bfh[4], bfl[4];
#pragma unroll
        for (int m = 0; m < 4; ++m) {
            const int e = (wr * 64 + m * 16 + (lane & 15)) * 32 + koff;
            afh[m] = *(const f16x8*)&lds[cur][0][e];
            afl[m] = *(const f16x8*)&lds[cur][1][e];
        }
#pragma unroll
        for (int n = 0; n < 4; ++n) {
            const int e = (wc * 64 + n * 16 + (lane & 15)) * 32 + koff;
            bfh[n] = *(const f16x8*)&lds[cur][2][e];
            bfl[n] = *(const f16x8*)&lds[cur][3][e];
        }
#pragma unroll
        for (int m = 0; m < 4; ++m)
#pragma unroll
            for (int n = 0; n < 4; ++n) {
                acc[m][n] = __builtin_amdgcn_mfma_f32_16x16x32_f16(afh[m], bfh[n], acc[m][n], 0, 0, 0);
                acc[m][n] = __builtin_amdgcn_mfma_f32_16x16x32_f16(afh[m], bfl[n], acc[m][n], 0, 0, 0);
                acc[m][n] = __builtin_amdgcn_mfma_f32_16x16x32_f16(afl[m], bfh[n], acc[m][n], 0, 0, 0);
            }
        __syncthreads();                 // single drain point, AFTER compute
    }

#pragma unroll
    for (int m = 0; m < 4; ++m) {
        const int rowc = row0 + wr * 64 + m * 16 + ((lane >> 4) << 2);
#pragma unroll
        for (int n = 0; n < 4; ++n) {
            const int colc = col0 + wc * 64 + n * 16 + (lane & 15);
#pragma unroll
            for (int j = 0; j < 4; ++j) {
                float v = acc[m][n][j] + bv[n];
                if (OUTMODE == 2) {
                    v = fmaxf(v, 0.f);
                    const size_t idx = (size_t)(rowc + j) * N + colc;
                    _Float16 h = (_Float16)v;
                    Ch[idx] = h;
                    Cl[idx] = (_Float16)(v - (float)h);
                } else {
                    Cf[(size_t)(rowc + j) * N + colc] = v;
                }
            }
        }
    }
}

// ---------------- fp32 GEMM (tiny head projections) -------------------------
template<int RELU>
__global__ __launch_bounds__(256) void gemm_bias(const float* __restrict__ A,
        const float* __restrict__ W, const float* __restrict__ bias,
        float* __restrict__ C, int M, int N, int K)
{
    __shared__ float As[8][128];
    __shared__ float Ws[8][128];
    const int tid = threadIdx.x;
    const int tn = tid & 15, tm = tid >> 4;
    const int row0 = blockIdx.y * 128, col0 = blockIdx.x * 128;
    const int lrr = tid >> 1, lcc = (tid & 1) * 4;
    const float* Ap = A + (size_t)(row0 + lrr) * K + lcc;
    const float* Wp = W + (size_t)(col0 + lrr) * K + lcc;
    float acc[8][8];
#pragma unroll
    for (int i = 0; i < 8; ++i)
#pragma unroll
        for (int j = 0; j < 8; ++j) acc[i][j] = 0.f;

    for (int k0 = 0; k0 < K; k0 += 8) {
        float4 av = *(const float4*)(Ap + k0);
        float4 wv = *(const float4*)(Wp + k0);
        __syncthreads();
        As[lcc + 0][lrr] = av.x; As[lcc + 1][lrr] = av.y;
        As[lcc + 2][lrr] = av.z; As[lcc + 3][lrr] = av.w;
        Ws[lcc + 0][lrr] = wv.x; Ws[lcc + 1][lrr] = wv.y;
        Ws[lcc + 2][lrr] = wv.z; Ws[lcc + 3][lrr] = wv.w;
        __syncthreads();
#pragma unroll
        for (int k = 0; k < 8; ++k) {
            float ar[8], wrg[8];
#pragma unroll
            for (int i = 0; i < 8; ++i) ar[i] = As[k][tm * 8 + i];
#pragma unroll
            for (int j = 0; j < 8; ++j) wrg[j] = Ws[k][tn * 8 + j];
#pragma unroll
            for (int i = 0; i < 8; ++i)
#pragma unroll
                for (int j = 0; j < 8; ++j)
                    acc[i][j] = fmaf(ar[i], wrg[j], acc[i][j]);
        }
    }
#pragma unroll
    for (int i = 0; i < 8; ++i) {
        const int r = row0 + tm * 8 + i;
#pragma unroll
        for (int j = 0; j < 8; ++j) {
            const int c = col0 + tn * 8 + j;
            float v = acc[i][j] + bias[c];
            if (RELU) v = fmaxf(v, 0.f);
            C[(size_t)r * N + c] = v;
        }
    }
}

// ---------------- Attention (writes split fp16 h/l output) ------------------
__global__ __launch_bounds__(128) void attn_kernel(const float* __restrict__ qkv,
        _Float16* __restrict__ oh, _Float16* __restrict__ ol)
{
    const int bh = blockIdx.x;
    const int b = bh >> 3, hh = bh & 7;
    const int t = threadIdx.x;
    __shared__ float Ks[S_LEN][HD];
    __shared__ float Vs[S_LEN][HD];
    const float* base = qkv + (size_t)b * S_LEN * (3 * D_MODEL);
    const float* krow = base + (size_t)t * (3 * D_MODEL) + D_MODEL + hh * HD;
    const float* vrow = base + (size_t)t * (3 * D_MODEL) + 2 * D_MODEL + hh * HD;
#pragma unroll
    for (int d = 0; d < HD; d += 4) {
        *(float4*)&Ks[t][d] = *(const float4*)(krow + d);
        *(float4*)&Vs[t][d] = *(const float4*)(vrow + d);
    }
    float q[HD];
    const float* qrow = base + (size_t)t * (3 * D_MODEL) + hh * HD;
#pragma unroll
    for (int d = 0; d < HD; d += 4) {
        float4 v4 = *(const float4*)(qrow + d);
        q[d] = v4.x; q[d + 1] = v4.y; q[d + 2] = v4.z; q[d + 3] = v4.w;
    }
    __syncthreads();
    float m = -1e30f, l = 0.f;
    float oacc[HD];
#pragma unroll
    for (int d = 0; d < HD; ++d) oacc[d] = 0.f;
    for (int j = 0; j < S_LEN; ++j) {
        float s = 0.f;
#pragma unroll
        for (int d = 0; d < HD; ++d) s = fmaf(q[d], Ks[j][d], s);
        s *= 0.125f;
        const float nm = fmaxf(m, s);
        const float sc = expf(m - nm);
        const float p = expf(s - nm);
        l = l * sc + p;
#pragma unroll
        for (int d = 0; d < HD; ++d) oacc[d] = oacc[d] * sc + p * Vs[j][d];
        m = nm;
    }
    const float inv = 1.f / l;
    const size_t ob = (size_t)b * S_LEN * D_MODEL + (size_t)t * D_MODEL + hh * HD;
#pragma unroll
    for (int d = 0; d < HD; ++d) {
        const float v = oacc[d] * inv;
        const _Float16 h = (_Float16)v;
        oh[ob + d] = h;
        ol[ob + d] = (_Float16)(v - (float)h);
    }
}

// ---------------- residual add + LayerNorm (+ optional split out) ----------
template<int SPLIT>
__global__ __launch_bounds__(128) void add_ln_kernel(const float* __restrict__ a,
        const float* __restrict__ bb, const float* __restrict__ g,
        const float* __restrict__ be, float* __restrict__ out,
        _Float16* __restrict__ oh, _Float16* __restrict__ ol)
{
    __shared__ float red[2];
    const int row = blockIdx.x, t = threadIdx.x;
    float4 av = *(const float4*)(a + (size_t)row * D_MODEL + t * 4);
    float4 bv = *(const float4*)(bb + (size_t)row * D_MODEL + t * 4);
    float x0 = av.x + bv.x, x1 = av.y + bv.y, x2 = av.z + bv.z, x3 = av.w + bv.w;
    float ssum = x0 + x1 + x2 + x3;
#pragma unroll
    for (int off = 32; off >= 1; off >>= 1) ssum += __shfl_xor(ssum, off);
    if ((t & 63) == 0) red[t >> 6] = ssum;
    __syncthreads();
    const float mean = (red[0] + red[1]) * (1.f / 512.f);
    __syncthreads();
    float d0 = x0 - mean, d1 = x1 - mean, d2 = x2 - mean, d3 = x3 - mean;
    float sq = d0 * d0 + d1 * d1 + d2 * d2 + d3 * d3;
#pragma unroll
    for (int off = 32; off >= 1; off >>= 1) sq += __shfl_xor(sq, off);
    if ((t & 63) == 0) red[t >> 6] = sq;
    __syncthreads();
    const float var = (red[0] + red[1]) * (1.f / 512.f);
    const float inv = 1.0f / sqrtf(var + 1e-5f);
    float4 gv = *(const float4*)(g + t * 4);
    float4 bev = *(const float4*)(be + t * 4);
    float4 ov = make_float4(d0 * inv * gv.x + bev.x, d1 * inv * gv.y + bev.y,
                            d2 * inv * gv.z + bev.z, d3 * inv * gv.w + bev.w);
    *(float4*)(out + (size_t)row * D_MODEL + t * 4) = ov;
    if (SPLIT) {
        f16x4 h, l;
        _Float16 h0 = (_Float16)ov.x; h[0] = h0; l[0] = (_Float16)(ov.x - (float)h0);
        _Float16 h1 = (_Float16)ov.y; h[1] = h1; l[1] = (_Float16)(ov.y - (float)h1);
        _Float16 h2 = (_Float16)ov.z; h[2] = h2; l[2] = (_Float16)(ov.z - (float)h2);
        _Float16 h3 = (_Float16)ov.w; h[3] = h3; l[3] = (_Float16)(ov.w - (float)h3);
        *(f16x4*)&oh[(size_t)row * D_MODEL + t * 4] = h;
        *(f16x4*)&ol[(size_t)row * D_MODEL + t * 4] = l;
    }
}

// ---------------- mean over sequence ---------------------------------------
__global__ __launch_bounds__(128) void pool_kernel(const float* __restrict__ x,
                                                   float* __restrict__ pooled)
{
    const int b = blockIdx.x, t = threadIdx.x;
    float4 acc = make_float4(0.f, 0.f, 0.f, 0.f);
    const float* base = x + (size_t)b * S_LEN * D_MODEL + t * 4;
    for (int s = 0; s < S_LEN; ++s) {
        float4 v = *(const float4*)(base + (size_t)s * D_MODEL);
        acc.x += v.x; acc.y += v.y; acc.z += v.z; acc.w += v.w;
    }
    const float sc = 1.f / 128.f;
    float4 ov = make_float4(acc.x * sc, acc.y * sc, acc.z * sc, acc.w * sc);
    *(float4*)(pooled + (size_t)b * D_MODEL + t * 4) = ov;
}

// ---------------- root-MUSIC: parallel Jacobi + register-shuffle DK --------
// DK: convergence-gated early exit (break only when ALL roots' |dz|<1e-12;
// post-convergence drift five orders below selection sensitivity).
__global__ __launch_bounds__(64) void music_kernel(const float* __restrict__ RxRy,
                                                   float* __restrict__ hbuf)
{
    const int pb = blockIdx.x;          // 0..511
    const int b = pb >> 1, which = pb & 1;
    const float* src = RxRy + (size_t)which * (B_SZ * 128) + (size_t)b * 128;
    const int t = threadIdx.x;
    const int i = t >> 3, j = t & 7;

    __shared__ double KRe[8][8], KIm[8][8];
    __shared__ double Ar[8][8], Ai[8][8], Vr[8][8], Vi[8][8];
    __shared__ double Fre[8][8], Fim[8][8];
    __shared__ double rc[4], rs[4], rer[4], rei[4];
    __shared__ double cr[15], ci[15], br[14], bi[14], zr[14], zi[14];
    __shared__ int topidx[3];

    KRe[i][j] = (double)src[i * 8 + j];
    KIm[i][j] = (double)src[64 + i * 8 + j];
    __syncthreads();
    {   // Rz = K^H K + I ; V = I
        double sre = (i == j) ? 1.0 : 0.0, sim = 0.0;
        for (int r = 0; r < 8; ++r) {
            const double ar = KRe[r][i], ai = KIm[r][i];
            const double xr = KRe[r][j], xi = KIm[r][j];
            sre += ar * xr + ai * xi;
            sim += ar * xi - ai * xr;
        }
        Ar[i][j] = sre; Ai[i][j] = sim;
        Vr[i][j] = (i == j) ? 1.0 : 0.0;
        Vi[i][j] = 0.0;
    }
    __syncthreads();

    // parallel-order Jacobi: JACOBI_SWEEPS x 7 rounds x 4 disjoint rotations
    for (int sw = 0; sw < JACOBI_SWEEPS; ++sw)
    for (int rr = 0; rr < 7; ++rr) {
        int pp[4], qq[4];
        pp[0] = 0;                 qq[0] = (rr + 6) % 7 + 1;
        pp[1] = rr % 7 + 1;        qq[1] = (rr + 5) % 7 + 1;
        pp[2] = (rr + 1) % 7 + 1;  qq[2] = (rr + 4) % 7 + 1;
        pp[3] = (rr + 2) % 7 + 1;  qq[3] = (rr + 3) % 7 + 1;
        if (t < 4) {
            const int p = pp[t], q = qq[t];
            const double gre = Ar[p][q], gim = Ai[p][q];
            const double r = sqrt(gre * gre + gim * gim);
            double c, s, er, ei;
            if (r < 1e-60) { c = 1.0; s = 0.0; er = 1.0; ei = 0.0; }
            else {
                const double tau = (Ar[p][p] - Ar[q][q]) / (2.0 * r);
                const double tt = ((tau >= 0.0) ? 1.0 : -1.0) /
                                  (fabs(tau) + sqrt(1.0 + tau * tau));
                c = 1.0 / sqrt(1.0 + tt * tt); s = tt * c;
                er = gre / r; ei = gim / r;
            }
            rc[t] = c; rs[t] = s; rer[t] = er; rei[t] = ei;
        }
        __syncthreads();
        int gi = 0, gj = 0;
#pragma unroll
        for (int g = 0; g < 4; ++g) {
            if (pp[g] == i || qq[g] == i) gi = g;
            if (pp[g] == j || qq[g] == j) gj = g;
        }
        const int ri_q = (qq[gi] == i), rj_q = (qq[gj] == j);
        const double ci_ = rc[gi], si_ = rs[gi], eir = rer[gi], eii = rei[gi];
        const double cj_ = rc[gj], sj_ = rs[gj], ejr = rer[gj], eji = rei[gj];
        const int Pi = pp[gi], Qi = qq[gi], Pj = pp[gj], Qj = qq[gj];

        double bPr, bPi_, bQr, bQi_;
        {
            double apr = Ar[Pi][Pj], api = Ai[Pi][Pj];
            double aqr = Ar[Pi][Qj], aqi = Ai[Pi][Qj];
            if (!rj_q) { bPr = cj_ * apr + sj_ * (ejr * aqr + eji * aqi);
                         bPi_= cj_ * api + sj_ * (ejr * aqi - eji * aqr); }
            else       { bPr = cj_ * aqr - sj_ * (ejr * apr - eji * api);
                         bPi_= cj_ * aqi - sj_ * (ejr * api + eji * apr); }
            apr = Ar[Qi][Pj]; api = Ai[Qi][Pj];
            aqr = Ar[Qi][Qj]; aqi = Ai[Qi][Qj];
            if (!rj_q) { bQr = cj_ * apr + sj_ * (ejr * aqr + eji * aqi);
                         bQi_= cj_ * api + sj_ * (ejr * aqi - eji * aqr); }
            else       { bQr = cj_ * aqr - sj_ * (ejr * apr - eji * api);
                         bQi_= cj_ * aqi - sj_ * (ejr * api + eji * apr); }
        }
        double nAr, nAi_;
        if (!ri_q) { nAr = ci_ * bPr + si_ * (eir * bQr - eii * bQi_);
                     nAi_= ci_ * bPi_+ si_ * (eir * bQi_ + eii * bQr); }
        else       { nAr = ci_ * bQr - si_ * (eir * bPr + eii * bPi_);
                     nAi_= ci_ * bQi_- si_ * (eir * bPi_ - eii * bPr); }
        double nVr, nVi_;
        {
            const double vpr = Vr[i][Pj], vpi = Vi[i][Pj];
            const double vqr = Vr[i][Qj], vqi = Vi[i][Qj];
            if (!rj_q) { nVr = cj_ * vpr + sj_ * (ejr * vqr + eji * vqi);
                         nVi_= cj_ * vpi + sj_ * (ejr * vqi - eji * vqr); }
            else       { nVr = cj_ * vqr - sj_ * (ejr * vpr - eji * vpi);
                         nVi_= cj_ * vqi - sj_ * (ejr * vpi + eji * vpr); }
        }
        __syncthreads();
        Ar[i][j] = nAr; Ai[i][j] = nAi_;
        Vr[i][j] = nVr; Vi[i][j] = nVi_;
        __syncthreads();
    }

    if (t == 0) {  // top-3 eigenvalues -> signal subspace
        bool used[8] = {false, false, false, false, false, false, false, false};
        for (int tt = 0; tt < 3; ++tt) {
            double best = -1e300; int bidx = 0;
            for (int k = 0; k < 8; ++k)
                if (!used[k] && Ar[k][k] > best) { best = Ar[k][k]; bidx = k; }
            used[bidx] = true; topidx[tt] = bidx;
        }
    }
    __syncthreads();
    {   // F = I - sum_top3 v v^H
        double fre = (i == j) ? 1.0 : 0.0, fim = 0.0;
        for (int tt = 0; tt < 3; ++tt) {
            const int e = topidx[tt];
            const double vir = Vr[i][e], vii = Vi[i][e];
            const double vjr = Vr[j][e], vji = Vi[j][e];
            fre -= vir * vjr + vii * vji;
            fim -= vii * vjr - vir * vji;
        }
        Fre[i][j] = fre; Fim[i][j] = fim;
    }
    __syncthreads();
    if (t < 15) {  // coeffs: diagonal sums
        const int o = t - 7;
        double sre = 0.0, sim = 0.0;
        for (int r = 0; r < 8; ++r) {
            const int cc = r + o;
            if (cc >= 0 && cc < 8) { sre += Fre[r][cc]; sim += Fim[r][cc]; }
        }
        cr[t] = sre; ci[t] = sim;
    }
    __syncthreads();
    if (t < 14) {  // monic normalize
        const double den = cr[0] * cr[0] + ci[0] * ci[0];
        const double nr = cr[t + 1], ni = ci[t + 1];
        br[t] = (nr * cr[0] + ni * ci[0]) / den;
        bi[t] = (ni * cr[0] - nr * ci[0]) / den;
    }
    __syncthreads();

    // ---- decimated Durand-Kerner, roots in registers, convergence-gated ---
    const int rt = t >> 2, jj = t & 3;
    const int rsafe = (rt < 14) ? rt : 0;
    double A_r[4], A_i[4];
#pragma unroll
    for (int m = 0; m < 4; ++m) {
        const int idx = 13 - 4 * m - jj;
        if (idx >= 0)       { A_r[m] = br[idx]; A_i[m] = bi[idx]; }
        else if (idx == -1) { A_r[m] = 1.0;     A_i[m] = 0.0; }
        else                { A_r[m] = 0.0;     A_i[m] = 0.0; }
    }

    double zre, zim;
    {   // init root rsafe: (0.4+0.9i)^(rsafe+1)
        double zr_ = 1.0, zi_ = 0.0;
        for (int k = 0; k <= rsafe; ++k) {
            const double a2 = zr_ * 0.4 - zi_ * 0.9;
            zi_ = zr_ * 0.9 + zi_ * 0.4;
            zr_ = a2;
        }
        zre = zr_; zim = zi_;
    }

    for (int it = 0; it < DK_ITERS; ++it) {
        const double z2r = zre * zre - zim * zim, z2i = 2.0 * zre * zim;
        const double yr = z2r * z2r - z2i * z2i, yi = 2.0 * z2r * z2i;
        double wre = A_r[3], wim = A_i[3];
#pragma unroll
        for (int m = 2; m >= 0; --m) {
            const double tr = wre * yr - wim * yi + A_r[m];
            wim = wre * yi + wim * yr + A_i[m];
            wre = tr;
        }
        double pr, pi;
        if (jj == 0)      { pr = wre; pi = wim; }
        else if (jj == 1) { pr = wre * zre - wim * zim; pi = wre * zim + wim * zre; }
        else if (jj == 2) { pr = wre * z2r - wim * z2i; pi = wre * z2i + wim * z2r; }
        else { const double z3r = z2r * zre - z2i * zim, z3i = z2r * zim + z2i * zre;
               pr = wre * z3r - wim * z3i; pi = wre * z3i + wim * z3r; }
        pr += __shfl_xor(pr, 1); pi += __shfl_xor(pi, 1);
        pr += __shfl_xor(pr, 2); pi += __shfl_xor(pi, 2);
        double dr = 1.0, di = 0.0;
#pragma unroll
        for (int q = 0; q < 4; ++q) {
            const int k = jj * 4 + q;                 // 0..15
            const double zkr = __shfl(zre, 4 * k);    // root k lives in lane 4k
            const double zki = __shfl(zim, 4 * k);
            const bool val = (k < 14) && (k != rsafe);
            const double exr = val ? (zre - zkr) : 1.0;
            const double exi = val ? (zim - zki) : 0.0;
            const double trd = dr * exr - di * exi;
            di = dr * exi + di * exr;
            dr = trd;
        }
        {
            double orr = __shfl_xor(dr, 1), oii = __shfl_xor(di, 1);
            double tr = dr * orr - di * oii; di = dr * oii + di * orr; dr = tr;
            orr = __shfl_xor(dr, 2); oii = __shfl_xor(di, 2);
            tr = dr * orr - di * oii; di = dr * oii + di * orr; dr = tr;
        }
        const double dd = dr * dr + di * di;
        double dzr, dzi;
        if (dd > 1e-260) {
            dzr = (pr * dr + pi * di) / dd;
            dzi = (pi * dr - pr * di) / dd;
        } else {
            dzr = -1e-8; dzi = 1e-8;
        }
        zre -= dzr; zim -= dzi;
        const bool conv = (rt >= 14) || (dzr * dzr + dzi * dzi < 1e-24);
        if (__all(conv)) break;
    }
    if (rt < 14 && jj == 0) { zr[rt] = zre; zi[rt] = zim; }
    __syncthreads();

    if (t == 0) {
        double keyv[14]; bool used[14];
        for (int k = 0; k < 14; ++k) {
            const double mag = sqrt(zr[k] * zr[k] + zi[k] * zi[k]);
            keyv[k] = fabs(mag - 1.0) + ((mag < 1.0) ? 0.0 : 1e6);
            used[k] = false;
        }
        for (int tt = 0; tt < 3; ++tt) {
            double best = 1e300; int bidx = 0;
            for (int k = 0; k < 14; ++k)
                if (!used[k] && keyv[k] < best) { best = keyv[k]; bidx = k; }
            used[bidx] = true;
            const double ang = atan2(zi[bidx], zr[bidx]);
            double ratio = ang / PI_D;
            if (ratio > 1.0) ratio = 1.0;
            if (ratio < -1.0) ratio = -1.0;
            hbuf[(size_t)b * 6 + which * 3 + tt] = (float)asin(ratio);
        }
    }
}

// ---------------- final MLP 6->256->256->6 ---------------------------------
__global__ __launch_bounds__(256) void mlp_kernel(const float* __restrict__ hbuf,
        const float* __restrict__ w1, const float* __restrict__ b1,
        const float* __restrict__ w2, const float* __restrict__ b2,
        const float* __restrict__ w3, const float* __restrict__ b3,
        float* __restrict__ outp)
{
    const int b = blockIdx.x, t = threadIdx.x;
    __shared__ float hin[8];
    __shared__ float h1[256];
    __shared__ float h2[256];
    if (t < 6) hin[t] = hbuf[b * 6 + t];
    __syncthreads();
    float acc = b1[t];
#pragma unroll
    for (int k = 0; k < 6; ++k) acc += hin[k] * w1[t * 6 + k];
    h1[t] = fmaxf(acc, 0.f);
    __syncthreads();
    float acc2 = b2[t];
    for (int k = 0; k < 256; ++k) acc2 += h1[k] * w2[t * 256 + k];
    h2[t] = fmaxf(acc2, 0.f);
    __syncthreads();
    if (t < 6) {
        float acc3 = b3[t];
        for (int k = 0; k < 256; ++k) acc3 += h2[k] * w3[t * 256 + k];
        if (t < 3) outp[b * 3 + t] = acc3;
        else       outp[B_SZ * 3 + b * 3 + (t - 3)] = acc3;
    }
}

// ---------------- host launcher --------------------------------------------
extern "C" void kernel_launch(void* const* d_in, const int* in_sizes, int n_in,
                              void* d_out, int out_size, void* d_ws, size_t ws_size,
                              hipStream_t stream)
{
    const float* x_in      = (const float*)d_in[0];
    const float* in_proj_w = (const float*)d_in[1];
    const float* in_proj_b = (const float*)d_in[2];
    const float* out_proj_w= (const float*)d_in[3];
    const float* out_proj_b= (const float*)d_in[4];
    const float* ln1_g     = (const float*)d_in[5];
    const float* ln1_b     = (const float*)d_in[6];
    const float* ffn_w1    = (const float*)d_in[7];
    const float* ffn_b1    = (const float*)d_in[8];
    const float* ffn_w2    = (const float*)d_in[9];
    const float* ffn_b2    = (const float*)d_in[10];
    const float* ln2_g     = (const float*)d_in[11];
    const float* ln2_b     = (const float*)d_in[12];
    const float* fcx_w     = (const float*)d_in[13];
    const float* fcx_b     = (const float*)d_in[14];
    const float* fcy_w     = (const float*)d_in[15];
    const float* fcy_b     = (const float*)d_in[16];
    const float* mlp_w1    = (const float*)d_in[17];
    const float* mlp_b1    = (const float*)d_in[18];
    const float* mlp_w2    = (const float*)d_in[19];
    const float* mlp_b2    = (const float*)d_in[20];
    const float* mlp_w3    = (const float*)d_in[21];
    const float* mlp_b3    = (const float*)d_in[22];

    // ---- workspace: split weights (static) --------------------------------
    const size_t N_IPW = 1536 * 512, N_OPW = 512 * 512;
    const size_t N_F1W = 2048 * 512, N_F2W = 512 * 2048;
    const size_t WCVT = N_IPW + N_OPW + N_F1W + N_F2W;   // 3,145,728 floats
    float* ws = (float*)d_ws;
    _Float16* ipw_h = (_Float16*)ws;
    _Float16* ipw_l = ipw_h + N_IPW;
    _Float16* opw_h = ipw_l + N_IPW;
    _Float16* opw_l = opw_h + N_OPW;
    _Float16* f1w_h = opw_l + N_OPW;
    _Float16* f1w_l = f1w_h + N_F1W;
    _Float16* f2w_h = f1w_l + N_F1W;
    _Float16* f2w_l = f2w_h + N_F2W;
    float* dyn = ws + WCVT;

    // ---- dynamic, chunked: 524288*c floats + tail -------------------------
    const size_t ws_floats = ws_size / sizeof(float);
    int c = 256;
    while (c > 1 && (size_t)524288 * (size_t)c + 262144 + WCVT > ws_floats) c >>= 1;

    float* R0     = dyn;                              // 262144c
    float* xhf    = R0 + (size_t)262144 * c;          // 32768c (xh f16)
    float* xlf    = xhf + (size_t)32768 * c;          // 32768c
    float* x1     = xlf + (size_t)32768 * c;          // 65536c fp32
    float* x1hf   = x1 + (size_t)65536 * c;           // 32768c
    float* x1lf   = x1hf + (size_t)32768 * c;         // 32768c
    float* ff2    = x1lf + (size_t)32768 * c;         // 65536c fp32
    float* pooled = ff2 + (size_t)65536 * c;          // 131072
    float* RxRy   = pooled + 131072;                  // 65536
    float* hbuf   = RxRy + 65536;                     // 1536

    float*    qkv  = R0;                              // 196608c fp32
    _Float16* oh   = (_Float16*)(R0 + (size_t)196608 * c);
    _Float16* ol   = oh + (size_t)65536 * c;
    _Float16* ff1h = (_Float16*)R0;                   // overlays qkv+o
    _Float16* ff1l = ff1h + (size_t)262144 * c;
    _Float16* xh   = (_Float16*)xhf;
    _Float16* xl   = (_Float16*)xlf;
    _Float16* x1h  = (_Float16*)x1hf;
    _Float16* x1l  = (_Float16*)x1lf;

    // ---- split weights ----------------------------------------------------
    cvt_split<<<(N_IPW / 4 + 255) / 256, 256, 0, stream>>>(in_proj_w,  ipw_h, ipw_l, N_IPW / 4);
    cvt_split<<<(N_OPW / 4 + 255) / 256, 256, 0, stream>>>(out_proj_w, opw_h, opw_l, N_OPW / 4);
    cvt_split<<<(N_F1W / 4 + 255) / 256, 256, 0, stream>>>(ffn_w1,     f1w_h, f1w_l, N_F1W / 4);
    cvt_split<<<(N_F2W / 4 + 255) / 256, 256, 0, stream>>>(ffn_w2,     f2w_h, f2w_l, N_F2W / 4);

    for (int b0 = 0; b0 < B_SZ; b0 += c) {
        const int Tc = c * S_LEN;
        const float* xc = x_in + (size_t)b0 * S_LEN * D_MODEL;
        const int n4x = Tc * D_MODEL / 4;

        // 0. split chunk input
        cvt_split<<<(n4x + 255) / 256, 256, 0, stream>>>(xc, xh, xl, n4x);
        // 1. qkv = x @ Wi^T + bi
        gemm_mfma<0><<<dim3(1536 / 128, Tc / 128), 256, 0, stream>>>(
            xh, xl, ipw_h, ipw_l, in_proj_b, qkv, nullptr, nullptr, Tc, 3 * D_MODEL, D_MODEL);
        // 2. attention -> split o
        attn_kernel<<<c * NHEADS, 128, 0, stream>>>(qkv, oh, ol);
        // 3. out proj
        gemm_mfma<0><<<dim3(512 / 128, Tc / 128), 256, 0, stream>>>(
            oh, ol, opw_h, opw_l, out_proj_b, x1, nullptr, nullptr, Tc, D_MODEL, D_MODEL);
        // 4. x1 = LN(x + proj), fp32 + split
        add_ln_kernel<1><<<Tc, 128, 0, stream>>>(xc, x1, ln1_g, ln1_b, x1, x1h, x1l);
        // 5. ff1 = relu(x1 @ W1^T + b1), split out (overlays dead qkv+o)
        gemm_mfma<2><<<dim3(DFFN / 128, Tc / 128), 256, 0, stream>>>(
            x1h, x1l, f1w_h, f1w_l, ffn_b1, nullptr, ff1h, ff1l, Tc, DFFN, D_MODEL);
        // 6. ff2 = ff1 @ W2^T + b2
        gemm_mfma<0><<<dim3(512 / 128, Tc / 128), 256, 0, stream>>>(
            ff1h, ff1l, f2w_h, f2w_l, ffn_b2, ff2, nullptr, nullptr, Tc, D_MODEL, DFFN);
        // 7. x2 = LN(x1 + ff2) in place (fp32 only)
        add_ln_kernel<0><<<Tc, 128, 0, stream>>>(x1, ff2, ln2_g, ln2_b, x1, nullptr, nullptr);
        // 8. mean pool
        pool_kernel<<<c, 128, 0, stream>>>(x1, pooled + (size_t)b0 * D_MODEL);
    }

    // 9. heads
    gemm_bias<0><<<dim3(1, 2), 256, 0, stream>>>(
        pooled, fcx_w, fcx_b, RxRy, B_SZ, 128, D_MODEL);
    gemm_bias<0><<<dim3(1, 2), 256, 0, stream>>>(
        pooled, fcy_w, fcy_b, RxRy + B_SZ * 128, B_SZ, 128, D_MODEL);
    // 10. root-MUSIC
    music_kernel<<<2 * B_SZ, 64, 0, stream>>>(RxRy, hbuf);
    // 11. final MLP
    mlp_kernel<<<B_SZ, 256, 0, stream>>>(hbuf, mlp_w1, mlp_b1, mlp_w2, mlp_b2,
                                         mlp_w3, mlp_b3, (float*)d_out);
}